// Round 2
// baseline (5281.753 us; speedup 1.0000x reference)
//
#include <hip/hip_runtime.h>
#include <hip/hip_bf16.h>
#include <math.h>

typedef __bf16 bf16;
typedef __bf16 bf16x8 __attribute__((ext_vector_type(8)));
typedef float  f32x4  __attribute__((ext_vector_type(4)));

#define MFMA16(a,b,c) __builtin_amdgcn_mfma_f32_16x16x32_bf16(a,b,c,0,0,0)

namespace {

constexpr int Bn = 128, Ln = 64, Tn = 48, En = 512, Hn = 512, Vn = 32000;
constexpr int G4 = 2048;          // 4*H
constexpr int TD = Tn - 1;        // 47 decode steps
constexpr int MD = TD * Bn;       // 6016 rows of the final GEMM
constexpr float NEGV = -1e9f;
constexpr int HB = Bn * Hn;       // 65536 elems per (B,H) state buffer

__device__ __forceinline__ float sigm(float x){ return 1.f/(1.f+__expf(-x)); }

// ---------------- fp32 -> bf16 conversion (vectorized x4) ----------------
__global__ void k_conv(const float4* __restrict__ s, ushort4* __restrict__ d, int n4){
  int i = blockIdx.x*256 + threadIdx.x;
  if (i >= n4) return;
  float4 v = s[i];
  union { bf16 h[4]; ushort4 u; } pk;
  pk.h[0]=(bf16)v.x; pk.h[1]=(bf16)v.y; pk.h[2]=(bf16)v.z; pk.h[3]=(bf16)v.w;
  d[i] = pk.u;
}

// ---------------- embedding gathers ----------------
// Xe layout: (L, B, E) rows (l*B+b), bf16
__global__ void k_gather_src(const int* __restrict__ toks, const float* __restrict__ emb,
                             ushort4* __restrict__ Xe){
  int i = blockIdx.x*256 + threadIdx.x;      // over L*B*E/4 = 1048576 (exact grid)
  int e4 = i & (En/4 - 1);
  int r  = i >> 7;
  int l = r >> 7, b = r & (Bn-1);
  int tok = toks[b*Ln + l];
  float4 v = *(const float4*)(emb + (size_t)tok*En + e4*4);
  union { bf16 h[4]; ushort4 u; } pk;
  pk.h[0]=(bf16)v.x; pk.h[1]=(bf16)v.y; pk.h[2]=(bf16)v.z; pk.h[3]=(bf16)v.w;
  Xe[i] = pk.u;
}

// Vg layout: (TD, B, E) rows (t*B+b), toks = trg_tokens[:, :-1]
__global__ void k_gather_trg(const int* __restrict__ toks, const float* __restrict__ emb,
                             ushort4* __restrict__ Vg){
  int i = blockIdx.x*256 + threadIdx.x;      // over TD*B*E/4 = 770048 (exact grid)
  int e4 = i & (En/4 - 1);
  int r  = i >> 7;
  int t = r >> 7, b = r & (Bn-1);
  int tok = toks[b*Tn + t];
  float4 v = *(const float4*)(emb + (size_t)tok*En + e4*4);
  union { bf16 h[4]; ushort4 u; } pk;
  pk.h[0]=(bf16)v.x; pk.h[1]=(bf16)v.y; pk.h[2]=(bf16)v.z; pk.h[3]=(bf16)v.w;
  Vg[i] = pk.u;
}

// ---------------- zero-init of states (ws is poisoned 0xAA every call) ----------------
__global__ void k_zero(bf16* __restrict__ a, bf16* __restrict__ b,
                       float* __restrict__ c, float* __restrict__ d,
                       float* __restrict__ outp){
  int i = blockIdx.x*256 + threadIdx.x;      // 65536 (exact)
  a[i] = (bf16)0.f; b[i] = (bf16)0.f; c[i] = 0.f; d[i] = 0.f;
  if (i == 0) outp[0] = 0.f;
}

// ---------------- generic bf16 MFMA GEMM: C = A(M,K=512) @ W(N,K=512)^T + bias ----------------
// MODE 0: store bf16 C.  MODE 1: fused per-row logsumexp partials (pmax/psum per 128-col chunk).
// Block: 512 thr = 8 waves; wave (wr,wc): rows wr*32(+2x16), cols wc*128(+8x16). BM=128, BN=256.
template<int MODE>
__global__ void __launch_bounds__(512) k_gemm(
    const bf16* __restrict__ A, const bf16* __restrict__ Bw,
    const float* __restrict__ bias, void* __restrict__ Ovp,
    float* __restrict__ pmax, float* __restrict__ psum,
    int Ncols, int Mrows)
{
  constexpr int K = 512;
  int lane = threadIdx.x & 63, w = threadIdx.x >> 6;
  int wr = w & 3, wc = w >> 2;
  int mt = blockIdx.x, nt = blockIdx.y;
  int mBase = mt*128 + wr*32;
  int nBase = nt*256 + wc*128;
  int laneK = (lane >> 4) * 8;
  const bf16* Ap = A  + (size_t)(mBase + (lane&15))*K + laneK;
  const bf16* Bp = Bw + (size_t)(nBase + (lane&15))*K + laneK;
  f32x4 acc[2][8] = {};
  for (int kb = 0; kb < K; kb += 32){
    bf16x8 a0 = *(const bf16x8*)(Ap + kb);
    bf16x8 a1 = *(const bf16x8*)(Ap + (size_t)16*K + kb);
    #pragma unroll
    for (int fn = 0; fn < 8; ++fn){
      bf16x8 bv = *(const bf16x8*)(Bp + (size_t)fn*16*K + kb);
      acc[0][fn] = MFMA16(a0, bv, acc[0][fn]);
      acc[1][fn] = MFMA16(a1, bv, acc[1][fn]);
    }
  }
  float bvv[8];
  #pragma unroll
  for (int fn = 0; fn < 8; ++fn) bvv[fn] = bias[nBase + fn*16 + (lane&15)];

  if constexpr (MODE == 0){
    bf16* O = (bf16*)Ovp;
    #pragma unroll
    for (int fm = 0; fm < 2; ++fm){
      #pragma unroll
      for (int r = 0; r < 4; ++r){
        size_t ro = (size_t)(mBase + fm*16 + ((lane>>4)<<2) + r) * Ncols;
        #pragma unroll
        for (int fn = 0; fn < 8; ++fn)
          O[ro + nBase + fn*16 + (lane&15)] = (bf16)(acc[fm][fn][r] + bvv[fn]);
      }
    }
  } else {
    int pc = nt*2 + wc;
    #pragma unroll
    for (int fm = 0; fm < 2; ++fm){
      #pragma unroll
      for (int r = 0; r < 4; ++r){
        float mx = -1e30f;
        #pragma unroll
        for (int fn = 0; fn < 8; ++fn) mx = fmaxf(mx, acc[fm][fn][r] + bvv[fn]);
        mx = fmaxf(mx, __shfl_xor(mx, 1));
        mx = fmaxf(mx, __shfl_xor(mx, 2));
        mx = fmaxf(mx, __shfl_xor(mx, 4));
        mx = fmaxf(mx, __shfl_xor(mx, 8));
        float sm = 0.f;
        #pragma unroll
        for (int fn = 0; fn < 8; ++fn) sm += __expf(acc[fm][fn][r] + bvv[fn] - mx);
        sm += __shfl_xor(sm, 1); sm += __shfl_xor(sm, 2);
        sm += __shfl_xor(sm, 4); sm += __shfl_xor(sm, 8);
        if ((lane & 15) == 0){
          int row = mBase + fm*16 + ((lane>>4)<<2) + r;
          pmax[(size_t)pc*Mrows + row] = mx;
          psum[(size_t)pc*Mrows + row] = sm;
        }
      }
    }
  }
}

// ---------------- K-loop helper for gate kernels ----------------
// acc[q] += A(16 rows) @ Wq(16 cols of quadrant q)^T over K=512.
__device__ __forceinline__ void kloop4(f32x4 acc[4], const bf16* __restrict__ Ap,
                                       const bf16* __restrict__ Wp, int ldw, int col)
{
  for (int kb = 0; kb < 512; kb += 32){
    bf16x8 a = *(const bf16x8*)(Ap + kb);
    #pragma unroll
    for (int q = 0; q < 4; ++q){
      bf16x8 bv = *(const bf16x8*)(Wp + (size_t)(q*Hn + col)*ldw + kb);
      acc[q] = MFMA16(a, bv, acc[q]);
    }
  }
}

// ---------------- fused encoder step (layer0 for t, layer1 for t-1, pipelined) ----------------
// Blocks 0..63: layer0 (E1). Blocks 64..127: layer1 (E2). 256 thr = 4 waves, wave = 16 h-cols.
__global__ void __launch_bounds__(256) k_enc(
    const bf16* __restrict__ Xg,
    bf16* __restrict__ h1b, bf16* __restrict__ h2b,
    float* __restrict__ c1, float* __restrict__ c2,
    const bf16* __restrict__ Whh0, const bf16* __restrict__ Wih1,
    const bf16* __restrict__ Whh1, const float* __restrict__ b1,
    const int* __restrict__ slens, bf16* __restrict__ Sst, int t)
{
  int bx = blockIdx.x;
  int lane = threadIdx.x & 63, w = threadIdx.x >> 6;
  bool isE2 = bx >= 64;
  int bb = isE2 ? bx - 64 : bx;
  int mt = bb >> 3, cg = bb & 7;
  int col  = cg*64 + w*16 + (lane & 15);
  int rowA = mt*16 + (lane & 15);
  int rowC = mt*16 + ((lane >> 4) << 2);
  int laneK = (lane >> 4) * 8;
  int rb = t & 1;

  if (!isE2){
    if (t >= Ln) return;
    f32x4 acc[4];
    #pragma unroll
    for (int q = 0; q < 4; ++q){
      #pragma unroll
      for (int r = 0; r < 4; ++r)
        acc[q][r] = (float)Xg[((size_t)(t*Bn + rowC + r))*G4 + q*Hn + col];
    }
    kloop4(acc, h1b + rb*HB + rowA*Hn + laneK, Whh0 + laneK, Hn, col);
    #pragma unroll
    for (int r = 0; r < 4; ++r){
      int grow = rowC + r;
      float cold = c1[grow*Hn + col];
      float iv = sigm(acc[0][r]), fv = sigm(acc[1][r]);
      float gv = tanhf(acc[2][r]), ov = sigm(acc[3][r]);
      float cn = fv*cold + iv*gv;
      float hn = ov*tanhf(cn);
      bool m = t < slens[grow];
      float hold = (float)h1b[rb*HB + grow*Hn + col];
      c1[grow*Hn + col] = m ? cn : cold;
      h1b[(rb^1)*HB + grow*Hn + col] = (bf16)(m ? hn : hold);
    }
  } else {
    int t2 = t - 1;
    if (t2 < 0) return;
    f32x4 acc[4];
    #pragma unroll
    for (int q = 0; q < 4; ++q){
      float bq = b1[q*Hn + col];
      #pragma unroll
      for (int r = 0; r < 4; ++r) acc[q][r] = bq;
    }
    // nh1 (written by E1 at launch t-1 into buf (t&1)); h2 ping-pong reads buf (t&1)
    kloop4(acc, h1b + rb*HB + rowA*Hn + laneK, Wih1 + laneK, Hn, col);
    kloop4(acc, h2b + rb*HB + rowA*Hn + laneK, Whh1 + laneK, Hn, col);
    #pragma unroll
    for (int r = 0; r < 4; ++r){
      int grow = rowC + r;
      float cold = c2[grow*Hn + col];
      float iv = sigm(acc[0][r]), fv = sigm(acc[1][r]);
      float gv = tanhf(acc[2][r]), ov = sigm(acc[3][r]);
      float cn = fv*cold + iv*gv;
      float hn = ov*tanhf(cn);
      bool m = t2 < slens[grow];
      float hold = (float)h2b[rb*HB + grow*Hn + col];
      c2[grow*Hn + col] = m ? cn : cold;
      h2b[(rb^1)*HB + grow*Hn + col] = (bf16)(m ? hn : hold);
      Sst[((size_t)grow*Ln + t2)*Hn + col] = m ? (bf16)hn : (bf16)0.f;
    }
  }
}

// ---------------- decoder init: c0 = [c1|c2] @ init_W^T + init_b ; h0 = tanh(c0) ----------------
__global__ void k_dec_init(const float* __restrict__ c1, const float* __restrict__ c2,
                           const float* __restrict__ iW, const float* __restrict__ ib,
                           float* __restrict__ cd, bf16* __restrict__ hdb)
{
  int n = blockIdx.x;          // 512 output cols
  int b = threadIdx.x;         // 128 rows
  float s = ib[n];
  const float* w0 = iW + (size_t)n*(2*Hn);
  for (int k = 0; k < Hn; ++k) s += c1[b*Hn + k] * w0[k];
  for (int k = 0; k < Hn; ++k) s += c2[b*Hn + k] * w0[Hn + k];
  cd[b*Hn + n] = s;
  hdb[b*Hn + n] = (bf16)tanhf(s);   // into hdb buf 0
}

// ---------------- decoder LSTM gates (input [v_t, av_{t-1}, h_{t-1}], K=1536) ----------------
__global__ void __launch_bounds__(256) k_dec1(
    const bf16* __restrict__ Vg, const bf16* __restrict__ av_all,
    bf16* __restrict__ hdb, float* __restrict__ cd,
    const bf16* __restrict__ Wdih, const bf16* __restrict__ Wdhh,
    const float* __restrict__ db, int t)
{
  int bb = blockIdx.x;
  int lane = threadIdx.x & 63, w = threadIdx.x >> 6;
  int mt = bb >> 3, cg = bb & 7;
  int col  = cg*64 + w*16 + (lane & 15);
  int rowA = mt*16 + (lane & 15);
  int rowC = mt*16 + ((lane >> 4) << 2);
  int laneK = (lane >> 4) * 8;
  int rb = t & 1;
  f32x4 acc[4];
  #pragma unroll
  for (int q = 0; q < 4; ++q){
    float bq = db[q*Hn + col];
    #pragma unroll
    for (int r = 0; r < 4; ++r) acc[q][r] = bq;
  }
  kloop4(acc, Vg + (size_t)t*Bn*En + rowA*En + laneK, Wdih + laneK, En+Hn, col);
  if (t > 0)
    kloop4(acc, av_all + (size_t)(t-1)*HB + rowA*Hn + laneK, Wdih + En + laneK, En+Hn, col);
  kloop4(acc, hdb + rb*HB + rowA*Hn + laneK, Wdhh + laneK, Hn, col);
  #pragma unroll
  for (int r = 0; r < 4; ++r){
    int grow = rowC + r;
    float cold = cd[grow*Hn + col];
    float iv = sigm(acc[0][r]), fv = sigm(acc[1][r]);
    float gv = tanhf(acc[2][r]), ov = sigm(acc[3][r]);
    float cn = fv*cold + iv*gv;
    float hn = ov*tanhf(cn);
    cd[grow*Hn + col] = cn;
    hdb[(rb^1)*HB + grow*Hn + col] = (bf16)hn;
  }
}

// ---------------- per-row attention: scores -> softmax (masked) -> ctx ----------------
__global__ void __launch_bounds__(256) k_attn(
    const bf16* __restrict__ hdb, const bf16* __restrict__ Sst,
    const int* __restrict__ slens, bf16* __restrict__ ctx, int t)
{
  int b = blockIdx.x, tid = threadIdx.x;
  const bf16* h = hdb + ((t&1)^1)*HB + (size_t)b*Hn;
  const bf16* S = Sst + (size_t)b*Ln*Hn;
  __shared__ float sc[Ln];
  __shared__ float at[Ln];
  int l = tid >> 2, kq = tid & 3;
  float s = 0.f;
  {
    const bf16* hp = h + kq*128;
    const bf16* Sp = S + (size_t)l*Hn + kq*128;
    for (int k8 = 0; k8 < 128; k8 += 8){
      bf16x8 hv = *(const bf16x8*)(hp + k8);
      bf16x8 sv = *(const bf16x8*)(Sp + k8);
      #pragma unroll
      for (int j = 0; j < 8; ++j) s += (float)hv[j]*(float)sv[j];
    }
  }
  s += __shfl_xor(s, 1); s += __shfl_xor(s, 2);
  if (kq == 0) sc[l] = (l < slens[b]) ? s : NEGV;
  __syncthreads();
  float mx = -1e30f;
  for (int j = 0; j < Ln; ++j) mx = fmaxf(mx, sc[j]);
  if (tid < Ln) at[tid] = __expf(sc[tid] - mx);
  __syncthreads();
  float den = 0.f;
  for (int j = 0; j < Ln; ++j) den += at[j];
  float inv = 1.f/den;
  for (int kk = tid; kk < Hn; kk += 256){
    float c = 0.f;
    for (int j = 0; j < Ln; ++j) c += at[j]*(float)S[(size_t)j*Hn + kk];
    ctx[(size_t)b*Hn + kk] = (bf16)(c*inv);
  }
}

// ---------------- hid projection: av = [h|ctx] @ hid_W^T + hid_b -> av_all[t] ----------------
__global__ void __launch_bounds__(256) k_hid(
    const bf16* __restrict__ hdb, const bf16* __restrict__ ctx,
    const bf16* __restrict__ Whid, const float* __restrict__ hbias,
    bf16* __restrict__ av_all, int t)
{
  int bb = blockIdx.x;
  int lane = threadIdx.x & 63, w = threadIdx.x >> 6;
  int mt = bb >> 3, cg = bb & 7;
  int col  = cg*64 + w*16 + (lane & 15);
  int rowA = mt*16 + (lane & 15);
  int rowC = mt*16 + ((lane >> 4) << 2);
  int laneK = (lane >> 4) * 8;
  int rb2 = (t & 1) ^ 1;
  float bq = hbias[col];
  f32x4 acc = {bq, bq, bq, bq};
  const bf16* Ah = hdb + rb2*HB + rowA*Hn + laneK;
  const bf16* Ac = ctx + rowA*Hn + laneK;
  const bf16* Wp = Whid + (size_t)col*(2*Hn) + laneK;
  for (int kb = 0; kb < 512; kb += 32){
    bf16x8 a  = *(const bf16x8*)(Ah + kb);
    bf16x8 bv = *(const bf16x8*)(Wp + kb);
    acc = MFMA16(a, bv, acc);
  }
  for (int kb = 0; kb < 512; kb += 32){
    bf16x8 a  = *(const bf16x8*)(Ac + kb);
    bf16x8 bv = *(const bf16x8*)(Wp + Hn + kb);
    acc = MFMA16(a, bv, acc);
  }
  #pragma unroll
  for (int r = 0; r < 4; ++r)
    av_all[(size_t)t*HB + (size_t)(rowC + r)*Hn + col] = (bf16)acc[r];
}

// ---------------- target logit: tlog[row] = av[row] . out_W[tgt] + out_b[tgt] ----------------
__global__ void k_tgt(const bf16* __restrict__ av_all, const bf16* __restrict__ Wout,
                      const float* __restrict__ ob, const int* __restrict__ trg_tokens,
                      float* __restrict__ tlog)
{
  int row = blockIdx.x*4 + (threadIdx.x >> 6);   // grid 1504 -> 6016 rows exact
  int lane = threadIdx.x & 63;
  int t = row >> 7, b = row & 127;
  int tok = trg_tokens[b*Tn + t + 1];
  bf16x8 va = *(const bf16x8*)(av_all + (size_t)row*Hn + lane*8);
  bf16x8 vw = *(const bf16x8*)(Wout + (size_t)tok*Hn + lane*8);
  float s = 0.f;
  #pragma unroll
  for (int j = 0; j < 8; ++j) s += (float)va[j]*(float)vw[j];
  #pragma unroll
  for (int sh = 1; sh < 64; sh <<= 1) s += __shfl_xor(s, sh);
  if (lane == 0) tlog[row] = s + ob[tok];
}

// ---------------- final reduce: lse per row, masked sum of (tlog - lse) ----------------
__global__ void k_lse(const float* __restrict__ pmax, const float* __restrict__ psum,
                      const float* __restrict__ tlog, const int* __restrict__ tlens,
                      float* __restrict__ out)
{
  int row = blockIdx.x*512 + threadIdx.x;
  float contrib = 0.f;
  if (row < MD){
    float mx = -1e30f;
    for (int pc = 0; pc < 250; ++pc) mx = fmaxf(mx, pmax[(size_t)pc*MD + row]);
    float s = 0.f;
    for (int pc = 0; pc < 250; ++pc)
      s += psum[(size_t)pc*MD + row] * __expf(pmax[(size_t)pc*MD + row] - mx);
    float lse = mx + __logf(s);
    int t = row >> 7, b = row & 127;
    if (t + 1 < tlens[b]) contrib = tlog[row] - lse;
  }
  #pragma unroll
  for (int sh = 1; sh < 64; sh <<= 1) contrib += __shfl_xor(contrib, sh);
  __shared__ float wsum[8];
  if ((threadIdx.x & 63) == 0) wsum[threadIdx.x >> 6] = contrib;
  __syncthreads();
  if (threadIdx.x == 0){
    float s2 = 0.f;
    for (int i = 0; i < 8; ++i) s2 += wsum[i];
    atomicAdd(out, s2);
  }
}

} // namespace

extern "C" void kernel_launch(void* const* d_in, const int* in_sizes, int n_in,
                              void* d_out, int out_size, void* d_ws, size_t ws_size,
                              hipStream_t stream)
{
  (void)in_sizes; (void)n_in; (void)out_size; (void)ws_size;
  const int*   src_tokens = (const int*)  d_in[0];
  const int*   src_lens   = (const int*)  d_in[1];
  const int*   trg_tokens = (const int*)  d_in[2];
  const int*   trg_lens   = (const int*)  d_in[3];
  const float* src_emb    = (const float*)d_in[4];
  const float* trg_emb    = (const float*)d_in[5];
  const float* eWih0 = (const float*)d_in[6];
  const float* eWhh0 = (const float*)d_in[7];
  const float* eb0   = (const float*)d_in[8];
  const float* eWih1 = (const float*)d_in[9];
  const float* eWhh1 = (const float*)d_in[10];
  const float* eb1   = (const float*)d_in[11];
  const float* dWih  = (const float*)d_in[12];
  const float* dWhh  = (const float*)d_in[13];
  const float* db    = (const float*)d_in[14];
  const float* hW    = (const float*)d_in[15];
  const float* hb    = (const float*)d_in[16];
  const float* oW    = (const float*)d_in[17];
  const float* ob    = (const float*)d_in[18];
  const float* iW    = (const float*)d_in[19];
  const float* ib    = (const float*)d_in[20];

  char* p = (char*)d_ws;
  auto alloc = [&](size_t bytes)->void*{
    void* r = (void*)p; p += (bytes + 255) & ~(size_t)255; return r;
  };
  bf16* wih0  = (bf16*)alloc((size_t)G4*En*2);
  bf16* whh0  = (bf16*)alloc((size_t)G4*Hn*2);
  bf16* wih1  = (bf16*)alloc((size_t)G4*Hn*2);
  bf16* whh1  = (bf16*)alloc((size_t)G4*Hn*2);
  bf16* wdih  = (bf16*)alloc((size_t)G4*(En+Hn)*2);
  bf16* wdhh  = (bf16*)alloc((size_t)G4*Hn*2);
  bf16* whid  = (bf16*)alloc((size_t)Hn*(2*Hn)*2);
  bf16* wout  = (bf16*)alloc((size_t)Vn*Hn*2);
  bf16* Xe    = (bf16*)alloc((size_t)Ln*Bn*En*2);
  bf16* Vg    = (bf16*)alloc((size_t)TD*Bn*En*2);
  bf16* Sst   = (bf16*)alloc((size_t)Bn*Ln*Hn*2);
  bf16* h1b   = (bf16*)alloc((size_t)2*HB*2);
  bf16* h2b   = (bf16*)alloc((size_t)2*HB*2);
  bf16* hdb   = (bf16*)alloc((size_t)2*HB*2);
  bf16* ctx   = (bf16*)alloc((size_t)HB*2);
  bf16* avall = (bf16*)alloc((size_t)TD*HB*2);
  bf16* Xg    = (bf16*)alloc((size_t)Ln*Bn*G4*2);
  float* c1   = (float*)alloc((size_t)HB*4);
  float* c2   = (float*)alloc((size_t)HB*4);
  float* cd   = (float*)alloc((size_t)HB*4);
  float* pmax = (float*)alloc((size_t)250*MD*4);
  float* psum = (float*)alloc((size_t)250*MD*4);
  float* tlog = (float*)alloc((size_t)MD*4);
  float* outp = (float*)d_out;

  auto conv = [&](const float* s, bf16* d, int n){
    int n4 = n/4;
    k_conv<<<(n4+255)/256, 256, 0, stream>>>((const float4*)s, (ushort4*)d, n4);
  };
  conv(eWih0, wih0, G4*En);
  conv(eWhh0, whh0, G4*Hn);
  conv(eWih1, wih1, G4*Hn);
  conv(eWhh1, whh1, G4*Hn);
  conv(dWih,  wdih, G4*(En+Hn));
  conv(dWhh,  wdhh, G4*Hn);
  conv(hW,    whid, Hn*2*Hn);
  conv(oW,    wout, Vn*Hn);

  k_gather_src<<<4096, 256, 0, stream>>>(src_tokens, src_emb, (ushort4*)Xe);
  k_gather_trg<<<3008, 256, 0, stream>>>(trg_tokens, trg_emb, (ushort4*)Vg);
  k_zero<<<256, 256, 0, stream>>>(h1b, h2b + HB, c1, c2, outp);

  // Phase A: Xg = Xe @ Wih0^T + b0   (M=8192, N=2048), bf16 out
  k_gemm<0><<<dim3(64, 8), 512, 0, stream>>>(Xe, wih0, eb0, Xg, nullptr, nullptr, G4, Ln*Bn);

  // Encoder: 65 pipelined launches (layer0 at t, layer1 at t-1)
  for (int t = 0; t <= Ln; ++t)
    k_enc<<<128, 256, 0, stream>>>(Xg, h1b, h2b, c1, c2, whh0, wih1, whh1, eb1,
                                   src_lens, Sst, t);

  k_dec_init<<<512, 128, 0, stream>>>(c1, c2, iW, ib, cd, hdb);

  // Decoder: 47 steps x {gates, attention, hid}
  for (int t = 0; t < TD; ++t){
    k_dec1<<<64, 256, 0, stream>>>(Vg, avall, hdb, cd, wdih, wdhh, db, t);
    k_attn<<<128, 256, 0, stream>>>(hdb, Sst, src_lens, ctx, t);
    k_hid<<<64, 256, 0, stream>>>(hdb, ctx, whid, hb, avall, t);
  }

  k_tgt<<<1504, 256, 0, stream>>>(avall, wout, ob, trg_tokens, tlog);

  // Phase E: fused logits + per-chunk logsumexp partials (M=6016, N=32000)
  k_gemm<1><<<dim3(47, 125), 512, 0, stream>>>(avall, wout, ob, nullptr, pmax, psum, Vn, MD);

  k_lse<<<12, 512, 0, stream>>>(pmax, psum, tlog, trg_lens, outp);
}